// Round 9
// baseline (708.863 us; speedup 1.0000x reference)
//
#include <hip/hip_runtime.h>
#include <hip/hip_bf16.h>

#define TN 131072      // total nodes (B*N)
#define NB 256         // batches
#define NN 512         // nodes per batch
#define FD 128         // per-layer feature dim
#define DD 512         // concat dim
#define NE 2097152     // edges
#define NL 4           // layers
#define KT 64          // src k-tile for Adj-GEMM
#define HALFD 256      // dst half processed at a time

typedef __attribute__((ext_vector_type(8))) short bf16x8;
typedef __attribute__((ext_vector_type(4))) float f32x4;

__device__ __forceinline__ float b2f(unsigned int u) {
    union { unsigned int i; float f; } c; c.i = u << 16; return c.f;
}
__device__ __forceinline__ unsigned short f2b(float f) {
    union { float f; unsigned int i; } c; c.f = f;
    unsigned int x = c.i;
    return (unsigned short)((x + 0x7fffu + ((x >> 16) & 1u)) >> 16);  // RNE
}
__device__ __forceinline__ uint4 packv8(const float* a) {
    uint4 p;
    p.x = (unsigned int)f2b(a[0]) | ((unsigned int)f2b(a[1]) << 16);
    p.y = (unsigned int)f2b(a[2]) | ((unsigned int)f2b(a[3]) << 16);
    p.z = (unsigned int)f2b(a[4]) | ((unsigned int)f2b(a[5]) << 16);
    p.w = (unsigned int)f2b(a[6]) | ((unsigned int)f2b(a[7]) << 16);
    return p;
}
// fast tanh: (e^{2x}-1)/(e^{2x}+1), clamped (bf16-exact saturation)
__device__ __forceinline__ float ftanh(float x) {
    float xc = fminf(fmaxf(x, -9.0f), 9.0f);
    float e = __expf(2.0f * xc);
    return (e - 1.0f) * __builtin_amdgcn_rcpf(e + 1.0f);
}

// ---------------- CSR build ----------------
__global__ void count_k(const int* __restrict__ dst, int* __restrict__ counts) {
    int e = blockIdx.x * blockDim.x + threadIdx.x;
    if (e < NE) atomicAdd(&counts[dst[e]], 1);
}

__global__ __launch_bounds__(512) void scan_b_k(const int* __restrict__ counts,
                                                int* __restrict__ row_ptr,
                                                int* __restrict__ cursor,
                                                float* __restrict__ degs) {
    __shared__ int ss[512];
    int b = blockIdx.x, t = threadIdx.x;
    int gid = b * NN + t;
    int c = counts[gid];
    ss[t] = c;
    __syncthreads();
    for (int off = 1; off < 512; off <<= 1) {
        int v = (t >= off) ? ss[t - off] : 0;
        __syncthreads();
        ss[t] += v;
        __syncthreads();
    }
    int excl = ss[t] - c;
    int base = b * (NN * 16) + excl;   // DEG=16
    row_ptr[gid] = base;
    cursor[gid]  = base;
    degs[gid]    = (float)(c + 1);
    if (b == NB - 1 && t == NN - 1) row_ptr[TN] = NE;
}

__global__ void fill_k(const int* __restrict__ src, const int* __restrict__ dst,
                       int* __restrict__ cursor, int* __restrict__ col_idx) {
    int e = blockIdx.x * blockDim.x + threadIdx.x;
    if (e < NE) {
        int p = atomicAdd(&cursor[dst[e]], 1);
        col_idx[p] = src[e];
    }
}

// ---------------- att_W transpose + bf16 cast:  Wt[n][k] = bf16(W[k][n]) ----------------
__global__ __launch_bounds__(256) void transpose_cast_k(const float* __restrict__ W,
                                                        unsigned short* __restrict__ Wt) {
    __shared__ float tile[32][33];
    int k0 = blockIdx.x * 32, n0 = blockIdx.y * 32;
    int tx = threadIdx.x & 31, ty = threadIdx.x >> 5;  // 32 x 8
    #pragma unroll
    for (int i = 0; i < 32; i += 8)
        tile[ty + i][tx] = W[(size_t)(k0 + ty + i) * DD + n0 + tx];
    __syncthreads();
    #pragma unroll
    for (int i = 0; i < 32; i += 8)
        Wt[(size_t)(n0 + ty + i) * DD + k0 + tx] = f2b(tile[tx][ty + i]);
}

// ---------------- conv_W transpose + bf16 cast per layer: Wt_l[o][f] = bf16(W_l[f][o]) ----
__global__ __launch_bounds__(256) void transp_convW_k(const float* __restrict__ W,
                                                      unsigned short* __restrict__ Wt) {
    __shared__ float tile[32][33];
    const float* Wl = W + (size_t)blockIdx.z * FD * FD;
    unsigned short* Wtl = Wt + (size_t)blockIdx.z * FD * FD;
    int f0 = blockIdx.x * 32, o0 = blockIdx.y * 32;
    int tx = threadIdx.x & 31, ty = threadIdx.x >> 5;
    #pragma unroll
    for (int i = 0; i < 32; i += 8)
        tile[ty + i][tx] = Wl[(size_t)(f0 + ty + i) * FD + o0 + tx];
    __syncthreads();
    #pragma unroll
    for (int i = 0; i < 32; i += 8)
        Wtl[(size_t)(o0 + ty + i) * FD + f0 + tx] = f2b(tile[tx][ty + i]);
}

// ---------------- fused all-layer conv v6: aggregation as dense Adj-GEMM on MFMA ----
// One block per batch, 1024 threads (16 waves). Per layer, per dst-half (256):
//   GEMM1: C1[feat 128][dst 256] = sum_src hT[feat][src] * Adj[dst][src]
//     K=512 tiled by 64: per k-tile {stage scr+zero Adj | scatter CSR + transpose
//     scr->hT | MFMA accumulate}.  Adj entries = edge multiplicity (+I), exact in bf16.
//   round C1 -> agg[dst][feat] bf16 (LDS), then GEMM2 (v5): Wt x agg^T, tanh -> cat.
__global__ __launch_bounds__(1024) void conv_all_k(
    const float* __restrict__ node_feat,      // [TN][FD] fp32
    const unsigned short* __restrict__ Wt,    // [NL*FD][FD] bf16 (out,f)
    const float* __restrict__ bias,           // [NL*FD]
    const int* __restrict__ rp, const int* __restrict__ ci,
    const float* __restrict__ degs,
    unsigned short* __restrict__ cat)         // [TN][DD] bf16
{
    __shared__ unsigned short Adj[HALFD * 72];   // 36,864 B [dst 256][src 64 +8]
    __shared__ unsigned short hT[128 * 72];      // 18,432 B [feat][src 64 +8]
    __shared__ unsigned short scr[64 * 136];     // 17,408 B [src 64][feat 128 +8]
    __shared__ unsigned short agg[HALFD * 136];  // 69,632 B [dst 256][feat 128 +8]
    const int tid = threadIdx.x;
    const int g0 = blockIdx.x * NN;
    const int lane = tid & 63, w = tid >> 6;
    const int lr = lane & 15, lh = lane >> 4;
    const int am = w & 3, bn = w >> 2;           // GEMM1: m-pair (feat), n-quad (dst)

    for (int l = 0; l < NL; l++) {
        for (int h = 0; h < 2; h++) {
            f32x4 acc1[2][4];
            #pragma unroll
            for (int mi = 0; mi < 2; mi++)
                #pragma unroll
                for (int ni = 0; ni < 4; ni++)
                    acc1[mi][ni] = (f32x4){0.f, 0.f, 0.f, 0.f};

            for (int kt = 0; kt < 8; kt++) {
                // ---- phase 1: stage scr (coalesced global rows) + zero Adj ----
                {
                    int src = tid >> 4, u = tid & 15;
                    int gsrc = g0 + kt * KT + src;
                    uint4 v;
                    if (l == 0) {
                        const float4* s4 = (const float4*)(node_feat + (size_t)gsrc * FD + u * 8);
                        float4 x = s4[0], y = s4[1];
                        float tmp[8] = {x.x, x.y, x.z, x.w, y.x, y.y, y.z, y.w};
                        v = packv8(tmp);
                    } else {
                        v = *(const uint4*)&cat[(size_t)gsrc * DD + (l - 1) * FD + u * 8];
                    }
                    *(uint4*)&scr[src * 136 + u * 8] = v;
                }
                {
                    uint4 z4 = {0u, 0u, 0u, 0u};
                    #pragma unroll
                    for (int z = 0; z < 3; z++) {
                        int idx = tid + z * 1024;
                        if (idx < HALFD * 9)
                            *(uint4*)&Adj[(idx / 9) * 72 + (idx % 9) * 8] = z4;
                    }
                }
                __syncthreads();

                // ---- phase 2a: scatter edges into Adj (4 owners/row, disjoint src stripes) ----
                {
                    int d = tid >> 2, q = tid & 3;
                    int gd = g0 + h * HALFD + d;
                    int rs = rp[gd], re = rp[gd + 1];
                    for (int j = rs; j < re; j++) {
                        int s = ci[j] - g0;
                        if ((s >> 6) == kt && ((s >> 4) & 3) == q) {
                            int cix = d * 72 + (s & 63);
                            Adj[cix] = f2b(b2f(Adj[cix]) + 1.0f);
                        }
                    }
                    int ss = h * HALFD + d;   // self edge (+I)
                    if ((ss >> 6) == kt && ((ss >> 4) & 3) == q) {
                        int cix = d * 72 + (ss & 63);
                        Adj[cix] = f2b(b2f(Adj[cix]) + 1.0f);
                    }
                }
                // ---- phase 2b: transpose scr -> hT (threads < 512; u32 col reads) ----
                if (tid < 512) {
                    int f2v = tid & 63, s8 = tid >> 6;   // feat pair, src octet
                    unsigned int cw[8];
                    #pragma unroll
                    for (int i = 0; i < 8; i++)
                        cw[i] = *(const unsigned int*)&scr[(s8 * 8 + i) * 136 + f2v * 2];
                    uint4 e0, e1;
                    e0.x = (cw[0] & 0xffffu) | (cw[1] << 16);
                    e0.y = (cw[2] & 0xffffu) | (cw[3] << 16);
                    e0.z = (cw[4] & 0xffffu) | (cw[5] << 16);
                    e0.w = (cw[6] & 0xffffu) | (cw[7] << 16);
                    e1.x = (cw[0] >> 16) | (cw[1] & 0xffff0000u);
                    e1.y = (cw[2] >> 16) | (cw[3] & 0xffff0000u);
                    e1.z = (cw[4] >> 16) | (cw[5] & 0xffff0000u);
                    e1.w = (cw[6] >> 16) | (cw[7] & 0xffff0000u);
                    *(uint4*)&hT[(2 * f2v) * 72 + s8 * 8] = e0;
                    *(uint4*)&hT[(2 * f2v + 1) * 72 + s8 * 8] = e1;
                }
                __syncthreads();

                // ---- phase 3: MFMA accumulate over this k-tile ----
                #pragma unroll
                for (int ks = 0; ks < 2; ks++) {
                    bf16x8 afr[2], bfr[4];
                    #pragma unroll
                    for (int mi = 0; mi < 2; mi++)
                        afr[mi] = *(const bf16x8*)&hT[((am * 2 + mi) * 16 + lr) * 72 + ks * 32 + lh * 8];
                    #pragma unroll
                    for (int ni = 0; ni < 4; ni++)
                        bfr[ni] = *(const bf16x8*)&Adj[((bn * 4 + ni) * 16 + lr) * 72 + ks * 32 + lh * 8];
                    #pragma unroll
                    for (int mi = 0; mi < 2; mi++)
                        #pragma unroll
                        for (int ni = 0; ni < 4; ni++)
                            acc1[mi][ni] = __builtin_amdgcn_mfma_f32_16x16x32_bf16(
                                afr[mi], bfr[ni], acc1[mi][ni], 0, 0, 0);
                }
                __syncthreads();   // before next kt overwrites Adj/hT/scr
            }

            // ---- GEMM1 epilogue: C1 (lane: 4 consecutive feats x 1 dst) -> agg bf16 ----
            #pragma unroll
            for (int mi = 0; mi < 2; mi++) {
                #pragma unroll
                for (int ni = 0; ni < 4; ni++) {
                    int fb = (am * 2 + mi) * 16 + lh * 4;
                    int dl = (bn * 4 + ni) * 16 + lr;
                    uint2 pk;
                    pk.x = (unsigned int)f2b(acc1[mi][ni][0]) | ((unsigned int)f2b(acc1[mi][ni][1]) << 16);
                    pk.y = (unsigned int)f2b(acc1[mi][ni][2]) | ((unsigned int)f2b(acc1[mi][ni][3]) << 16);
                    *(uint2*)&agg[dl * 136 + fb] = pk;
                }
            }
            __syncthreads();   // agg complete

            // ---- GEMM2 (v5): lin = Wt x agg^T, tanh((lin+b)*rdeg) -> cat ----
            {
                int mo = w >> 1, ng = w & 1;
                bf16x8 af2[4];
                #pragma unroll
                for (int ks = 0; ks < 4; ks++)
                    af2[ks] = *(const bf16x8*)&Wt[((size_t)l * FD + mo * 16 + lr) * FD + ks * 32 + lh * 8];
                float4 bs = *(const float4*)&bias[l * FD + mo * 16 + lh * 4];
                #pragma unroll
                for (int dt = 0; dt < 8; dt++) {
                    int dl = (ng * 8 + dt) * 16 + lr;
                    f32x4 c2 = (f32x4){0.f, 0.f, 0.f, 0.f};
                    #pragma unroll
                    for (int ks = 0; ks < 4; ks++) {
                        bf16x8 bfv = *(const bf16x8*)&agg[dl * 136 + ks * 32 + lh * 8];
                        c2 = __builtin_amdgcn_mfma_f32_16x16x32_bf16(af2[ks], bfv, c2, 0, 0, 0);
                    }
                    int gd = g0 + h * HALFD + dl;
                    float rd = __builtin_amdgcn_rcpf(degs[gd]);
                    float t0 = ftanh((c2[0] + bs.x) * rd);
                    float t1 = ftanh((c2[1] + bs.y) * rd);
                    float t2 = ftanh((c2[2] + bs.z) * rd);
                    float t3 = ftanh((c2[3] + bs.w) * rd);
                    uint2 pk;
                    pk.x = (unsigned int)f2b(t0) | ((unsigned int)f2b(t1) << 16);
                    pk.y = (unsigned int)f2b(t2) | ((unsigned int)f2b(t3) << 16);
                    *(uint2*)&cat[(size_t)gd * DD + l * FD + mo * 16 + lh * 4] = pk;
                }
            }
            __syncthreads();   // half done: Adj/hT/scr/agg reusable; cat visible in-block
        }
    }
}

// ---------------- attention scores: bf16 MFMA GEMM + fused tanh/dot-v ----------------
// 1D grid 4096, XCD-swizzled so each XCD sweeps a contiguous m-range.
__global__ __launch_bounds__(256) void scores_k(
    const unsigned short* __restrict__ X,   // [TN][DD] bf16
    const unsigned short* __restrict__ Wt,  // [DD][DD] bf16, (n,k)
    const float* __restrict__ bv, const float* __restrict__ vv,
    float* __restrict__ sp)                 // [TN][8] partials
{
    __shared__ unsigned short sX[128][72];
    __shared__ unsigned short sW[128][72];
    int bid = blockIdx.x;
    int swz = (bid & 7) * 512 + (bid >> 3);   // 4096 blocks, 8 XCDs
    int bx = swz >> 2, by = swz & 3;
    int tid = threadIdx.x;
    int lane = tid & 63, wid = tid >> 6;
    int wm = wid >> 1, wn = wid & 1;
    int m0 = bx * 128;
    int n0 = by * 128;
    int lr = lane & 15, lh = lane >> 4;

    f32x4 acc[4][4];
    #pragma unroll
    for (int mi = 0; mi < 4; mi++)
        #pragma unroll
        for (int ni = 0; ni < 4; ni++)
            acc[mi][ni] = (f32x4){0.f, 0.f, 0.f, 0.f};

    for (int k0 = 0; k0 < DD; k0 += 64) {
        __syncthreads();
        #pragma unroll
        for (int i = 0; i < 4; i++) {
            int idx = tid + i * 256;
            int row = idx >> 3, ch = idx & 7;
            *(float4*)&sX[row][ch * 8] = *(const float4*)&X[(size_t)(m0 + row) * DD + k0 + ch * 8];
            *(float4*)&sW[row][ch * 8] = *(const float4*)&Wt[(size_t)(n0 + row) * DD + k0 + ch * 8];
        }
        __syncthreads();
        #pragma unroll
        for (int kk = 0; kk < 64; kk += 32) {
            bf16x8 af[4], bfr[4];
            #pragma unroll
            for (int mi = 0; mi < 4; mi++)
                af[mi] = *(const bf16x8*)&sX[wm * 64 + mi * 16 + lr][kk + lh * 8];
            #pragma unroll
            for (int ni = 0; ni < 4; ni++)
                bfr[ni] = *(const bf16x8*)&sW[wn * 64 + ni * 16 + lr][kk + lh * 8];
            #pragma unroll
            for (int mi = 0; mi < 4; mi++)
                #pragma unroll
                for (int ni = 0; ni < 4; ni++)
                    acc[mi][ni] = __builtin_amdgcn_mfma_f32_16x16x32_bf16(
                        af[mi], bfr[ni], acc[mi][ni], 0, 0, 0);
        }
    }

    float vcol[4], bcol[4];
    #pragma unroll
    for (int ni = 0; ni < 4; ni++) {
        int col = n0 + wn * 64 + ni * 16 + lr;
        vcol[ni] = vv[col];
        bcol[ni] = bv[col];
    }
    #pragma unroll
    for (int mi = 0; mi < 4; mi++) {
        #pragma unroll
        for (int r = 0; r < 4; r++) {
            float part = 0.f;
            #pragma unroll
            for (int ni = 0; ni < 4; ni++)
                part += ftanh(acc[mi][ni][r] + bcol[ni]) * vcol[ni];
            part += __shfl_xor(part, 1);
            part += __shfl_xor(part, 2);
            part += __shfl_xor(part, 4);
            part += __shfl_xor(part, 8);
            if (lr == 0) {
                int row = m0 + wm * 64 + mi * 16 + lh * 4 + r;
                sp[(size_t)row * 8 + by * 2 + wn] = part;
            }
        }
    }
}

// ---------------- softmax + pool (one block per batch) ----------------
__global__ __launch_bounds__(256) void pool_k(
    const float* __restrict__ sp, const unsigned short* __restrict__ X,
    float* __restrict__ pooled)
{
    __shared__ float sattn[512];
    __shared__ float wred[8];
    int b = blockIdx.x, t = threadIdx.x;
    float s0, s1;
    {
        const float4* p = (const float4*)&sp[((size_t)b * NN + t) * 8];
        float4 x = p[0], y = p[1];
        s0 = x.x + x.y + x.z + x.w + y.x + y.y + y.z + y.w;
        p = (const float4*)&sp[((size_t)b * NN + 256 + t) * 8];
        x = p[0]; y = p[1];
        s1 = x.x + x.y + x.z + x.w + y.x + y.y + y.z + y.w;
    }
    float m = fmaxf(s0, s1);
    #pragma unroll
    for (int off = 1; off < 64; off <<= 1) m = fmaxf(m, __shfl_xor(m, off));
    int wid = t >> 6, lane = t & 63;
    if (lane == 0) wred[wid] = m;
    __syncthreads();
    m = fmaxf(fmaxf(wred[0], wred[1]), fmaxf(wred[2], wred[3]));
    float e0 = expf(s0 - m), e1 = expf(s1 - m);
    float ssum = e0 + e1;
    #pragma unroll
    for (int off = 1; off < 64; off <<= 1) ssum += __shfl_xor(ssum, off);
    if (lane == 0) wred[4 + wid] = ssum;
    __syncthreads();
    float inv = 1.0f / (wred[4] + wred[5] + wred[6] + wred[7]);
    sattn[t] = e0 * inv;
    sattn[t + 256] = e1 * inv;
    __syncthreads();
    float2 acc = {0.f, 0.f};
    const unsigned short* Xb = X + (size_t)b * NN * DD;
    #pragma unroll 4
    for (int n = 0; n < NN; n++) {
        float a = sattn[n];
        unsigned int px = *(const unsigned int*)&Xb[(size_t)n * DD + t * 2];
        acc.x += a * b2f(px & 0xffff);
        acc.y += a * b2f(px >> 16);
    }
    pooled[b * DD + t * 2 + 0] = acc.x;
    pooled[b * DD + t * 2 + 1] = acc.y;
}

// ---------------- output layer ----------------
__global__ void out_k(const float* __restrict__ pooled, const float* __restrict__ Wo,
                      const float* __restrict__ bo, float* __restrict__ out) {
    int b = blockIdx.x, c = threadIdx.x;  // 128 threads
    float acc = 0.f;
    const float* p = pooled + b * DD;
    for (int k = 0; k < DD; k++) acc += p[k] * Wo[k * 128 + c];
    out[b * 128 + c] = fmaxf(acc + bo[c], 0.f);
}

extern "C" void kernel_launch(void* const* d_in, const int* in_sizes, int n_in,
                              void* d_out, int out_size, void* d_ws, size_t ws_size,
                              hipStream_t stream)
{
    const float* node_feat = (const float*)d_in[0];
    const int*   edge_src  = (const int*)d_in[1];
    const int*   edge_dst  = (const int*)d_in[2];
    const float* conv_W    = (const float*)d_in[3];
    const float* conv_b    = (const float*)d_in[4];
    const float* att_W     = (const float*)d_in[5];
    const float* att_b     = (const float*)d_in[6];
    const float* att_v     = (const float*)d_in[7];
    const float* out_W     = (const float*)d_in[8];
    const float* out_b     = (const float*)d_in[9];
    float* out = (float*)d_out;
    (void)in_sizes; (void)n_in; (void)out_size;

    char* ws = (char*)d_ws;
    size_t off = 0;
    auto alloc = [&](size_t bytes) {
        void* p = ws + off;
        off += (bytes + 255) & ~(size_t)255;
        return p;
    };
    unsigned short* cat   = (unsigned short*)alloc((size_t)TN * DD * 2);  // bf16
    int*   counts  = (int*)alloc((size_t)TN * 4);
    int*   row_ptr = (int*)alloc((size_t)(TN + 1) * 4);
    int*   cursor  = (int*)alloc((size_t)TN * 4);
    int*   col_idx = (int*)alloc((size_t)NE * 4);
    float* degs    = (float*)alloc((size_t)TN * 4);
    float* sp      = (float*)alloc((size_t)TN * 8 * 4);
    unsigned short* attWt = (unsigned short*)alloc((size_t)DD * DD * 2);  // bf16
    unsigned short* convWt = (unsigned short*)alloc((size_t)NL * FD * FD * 2);
    float* pooled  = (float*)alloc((size_t)NB * DD * 4);
    if (off > ws_size) return;  // diagnostic guard

    hipMemsetAsync(counts, 0, (size_t)TN * 4, stream);
    count_k<<<NE / 256, 256, 0, stream>>>(edge_dst, counts);
    scan_b_k<<<NB, 512, 0, stream>>>(counts, row_ptr, cursor, degs);
    fill_k<<<NE / 256, 256, 0, stream>>>(edge_src, edge_dst, cursor, col_idx);
    transpose_cast_k<<<dim3(DD / 32, DD / 32), 256, 0, stream>>>(att_W, attWt);
    transp_convW_k<<<dim3(FD / 32, FD / 32, NL), 256, 0, stream>>>(conv_W, convWt);

    conv_all_k<<<NB, 1024, 0, stream>>>(node_feat, convWt, conv_b,
                                        row_ptr, col_idx, degs, cat);

    scores_k<<<4096, 256, 0, stream>>>(cat, attWt, att_b, att_v, sp);
    pool_k<<<NB, 256, 0, stream>>>(sp, cat, pooled);
    out_k<<<NB, 128, 0, stream>>>(pooled, out_W, out_b, out);
}

// Round 10
// 482.231 us; speedup vs baseline: 1.4700x; 1.4700x over previous
//
#include <hip/hip_runtime.h>
#include <hip/hip_bf16.h>

#define TN 131072      // total nodes (B*N)
#define NB 256         // batches
#define NN 512         // nodes per batch
#define FD 128         // per-layer feature dim
#define DD 512         // concat dim
#define NE 2097152     // edges
#define NL 4           // layers
#define PITCH 136      // LDS row pitch in bf16 units (272 B)
#define CHK 32         // dst nodes per chunk (double-buffered agg)

typedef __attribute__((ext_vector_type(8))) short bf16x8;
typedef __attribute__((ext_vector_type(4))) float f32x4;

__device__ __forceinline__ float b2f(unsigned int u) {
    union { unsigned int i; float f; } c; c.i = u << 16; return c.f;
}
__device__ __forceinline__ unsigned short f2b(float f) {
    union { float f; unsigned int i; } c; c.f = f;
    unsigned int x = c.i;
    return (unsigned short)((x + 0x7fffu + ((x >> 16) & 1u)) >> 16);  // RNE
}
__device__ __forceinline__ void add2(float& a0, float& a1, unsigned int v) {
    union { unsigned int u; float f; } lo, hi;
    lo.u = v << 16; hi.u = v & 0xffff0000u;
    a0 += lo.f; a1 += hi.f;
}
__device__ __forceinline__ void set2(float& a0, float& a1, unsigned int v) {
    union { unsigned int u; float f; } lo, hi;
    lo.u = v << 16; hi.u = v & 0xffff0000u;
    a0 = lo.f; a1 = hi.f;
}
__device__ __forceinline__ uint4 packv8(const float* a) {
    uint4 p;
    p.x = (unsigned int)f2b(a[0]) | ((unsigned int)f2b(a[1]) << 16);
    p.y = (unsigned int)f2b(a[2]) | ((unsigned int)f2b(a[3]) << 16);
    p.z = (unsigned int)f2b(a[4]) | ((unsigned int)f2b(a[5]) << 16);
    p.w = (unsigned int)f2b(a[6]) | ((unsigned int)f2b(a[7]) << 16);
    return p;
}
// fast tanh: (e^{2x}-1)/(e^{2x}+1), clamped (bf16-exact saturation)
__device__ __forceinline__ float ftanh(float x) {
    float xc = fminf(fmaxf(x, -9.0f), 9.0f);
    float e = __expf(2.0f * xc);
    return (e - 1.0f) * __builtin_amdgcn_rcpf(e + 1.0f);
}

// ---------------- CSR build ----------------
__global__ void count_k(const int* __restrict__ dst, int* __restrict__ counts) {
    int e = blockIdx.x * blockDim.x + threadIdx.x;
    if (e < NE) atomicAdd(&counts[dst[e]], 1);
}

__global__ __launch_bounds__(512) void scan_b_k(const int* __restrict__ counts,
                                                int* __restrict__ row_ptr,
                                                int* __restrict__ cursor,
                                                float* __restrict__ degs) {
    __shared__ int ss[512];
    int b = blockIdx.x, t = threadIdx.x;
    int gid = b * NN + t;
    int c = counts[gid];
    ss[t] = c;
    __syncthreads();
    for (int off = 1; off < 512; off <<= 1) {
        int v = (t >= off) ? ss[t - off] : 0;
        __syncthreads();
        ss[t] += v;
        __syncthreads();
    }
    int excl = ss[t] - c;
    int base = b * (NN * 16) + excl;   // DEG=16
    row_ptr[gid] = base;
    cursor[gid]  = base;
    degs[gid]    = (float)(c + 1);
    if (b == NB - 1 && t == NN - 1) row_ptr[TN] = NE;
}

__global__ void fill_k(const int* __restrict__ src, const int* __restrict__ dst,
                       int* __restrict__ cursor, int* __restrict__ col_idx) {
    int e = blockIdx.x * blockDim.x + threadIdx.x;
    if (e < NE) {
        int p = atomicAdd(&cursor[dst[e]], 1);
        col_idx[p] = src[e];
    }
}

// ---------------- att_W transpose + bf16 cast:  Wt[n][k] = bf16(W[k][n]) ----------------
__global__ __launch_bounds__(256) void transpose_cast_k(const float* __restrict__ W,
                                                        unsigned short* __restrict__ Wt) {
    __shared__ float tile[32][33];
    int k0 = blockIdx.x * 32, n0 = blockIdx.y * 32;
    int tx = threadIdx.x & 31, ty = threadIdx.x >> 5;  // 32 x 8
    #pragma unroll
    for (int i = 0; i < 32; i += 8)
        tile[ty + i][tx] = W[(size_t)(k0 + ty + i) * DD + n0 + tx];
    __syncthreads();
    #pragma unroll
    for (int i = 0; i < 32; i += 8)
        Wt[(size_t)(n0 + ty + i) * DD + k0 + tx] = f2b(tile[tx][ty + i]);
}

// ---------------- conv_W transpose + bf16 cast per layer: Wt_l[o][f] = bf16(W_l[f][o]) ----
__global__ __launch_bounds__(256) void transp_convW_k(const float* __restrict__ W,
                                                      unsigned short* __restrict__ Wt) {
    __shared__ float tile[32][33];
    const float* Wl = W + (size_t)blockIdx.z * FD * FD;
    unsigned short* Wtl = Wt + (size_t)blockIdx.z * FD * FD;
    int f0 = blockIdx.x * 32, o0 = blockIdx.y * 32;
    int tx = threadIdx.x & 31, ty = threadIdx.x >> 5;
    #pragma unroll
    for (int i = 0; i < 32; i += 8)
        tile[ty + i][tx] = Wl[(size_t)(f0 + ty + i) * FD + o0 + tx];
    __syncthreads();
    #pragma unroll
    for (int i = 0; i < 32; i += 8)
        Wtl[(size_t)(o0 + ty + i) * FD + f0 + tx] = f2b(tile[tx][ty + i]);
}

// ---------------- fused all-layer conv v5b: dbuf agg, 1 barrier/chunk, 8-deep gather ----
// One block per batch, 1024 threads (16 waves). hW window in LDS (pitch-136).
// Chunk = 32 dst nodes, agg double-buffered. Per chunk bracket:
//   [MFMA(c)+epilogue from agg[cur]  ->  gather(c+1) into agg[cur^1]] -> barrier
// Gather: wave-uniform, 32 lanes per node (8B each); 8-deep load-then-add split
// keeps 8 LDS reads outstanding per lane (latency -> throughput).
__global__ __launch_bounds__(1024) void conv_all_k(
    const float* __restrict__ node_feat,      // [TN][FD] fp32
    const unsigned short* __restrict__ Wt,    // [NL*FD][FD] bf16 (out,f)
    const float* __restrict__ bias,           // [NL*FD]
    const int* __restrict__ rp, const int* __restrict__ ci,
    const float* __restrict__ degs,
    unsigned short* __restrict__ cat)         // [TN][DD] bf16
{
    __shared__ unsigned short hW[NN * PITCH];        // 139,264 B
    __shared__ unsigned short agg[2][CHK * PITCH];   // 2 x 8,704 B
    const int tid = threadIdx.x;
    const int g0 = blockIdx.x * NN;
    const int lane = tid & 63, w = tid >> 6;
    const int lr = lane & 15, lh = lane >> 4;
    const int mo = w >> 1, nd = w & 1;     // mfma: 8(out-tiles) x 2(dst-tiles)
    const int gn = tid >> 5;               // gather: node in chunk (0..31)
    const int gs = tid & 31;               // gather: 8B unit (4 feats) in row

    // initial stage: node_feat fp32 -> hW bf16
    #pragma unroll
    for (int i = 0; i < 8; i++) {
        int u = tid + i * 1024;
        int row = u >> 4, cu = u & 15;
        const float4* s4 = (const float4*)(node_feat + (size_t)(g0 + row) * FD + cu * 8);
        float4 x = s4[0], y = s4[1];
        float tmp[8] = {x.x, x.y, x.z, x.w, y.x, y.y, y.z, y.w};
        *(uint4*)&hW[row * PITCH + cu * 8] = packv8(tmp);
    }
    __syncthreads();

    // gather one chunk's aggregation into buf (add order = edge index order)
    auto gather = [&](int c, unsigned short* buf) {
        int nl = c * CHK + gn;                 // node index within batch
        unsigned int v = *(const unsigned int*)&hW[nl * PITCH + gs * 4];
        unsigned int v2 = *(const unsigned int*)&hW[nl * PITCH + gs * 4 + 2];
        float a0, a1, a2, a3;
        set2(a0, a1, v); set2(a2, a3, v2);
        int gnode = g0 + nl;
        int rs = rp[gnode], re = rp[gnode + 1];
        int j = rs;
        for (; j + 8 <= re; j += 8) {
            uint2 u[8];
            #pragma unroll
            for (int i = 0; i < 8; i++) {
                int s = ci[j + i] - g0;
                u[i] = *(const uint2*)&hW[s * PITCH + gs * 4];
            }
            #pragma unroll
            for (int i = 0; i < 8; i++) {
                add2(a0, a1, u[i].x); add2(a2, a3, u[i].y);
            }
        }
        for (; j + 2 <= re; j += 2) {
            int s0 = ci[j] - g0, s1 = ci[j + 1] - g0;
            uint2 u0 = *(const uint2*)&hW[s0 * PITCH + gs * 4];
            uint2 u1 = *(const uint2*)&hW[s1 * PITCH + gs * 4];
            add2(a0, a1, u0.x); add2(a2, a3, u0.y);
            add2(a0, a1, u1.x); add2(a2, a3, u1.y);
        }
        if (j < re) {
            int s0 = ci[j] - g0;
            uint2 u0 = *(const uint2*)&hW[s0 * PITCH + gs * 4];
            add2(a0, a1, u0.x); add2(a2, a3, u0.y);
        }
        uint2 pk;
        pk.x = (unsigned int)f2b(a0) | ((unsigned int)f2b(a1) << 16);
        pk.y = (unsigned int)f2b(a2) | ((unsigned int)f2b(a3) << 16);
        *(uint2*)&buf[gn * PITCH + gs * 4] = pk;
    };

    for (int l = 0; l < NL; l++) {
        // Wt fragments (A operand, m=out) + bias in regs for the whole layer
        bf16x8 af[4];
        #pragma unroll
        for (int ks = 0; ks < 4; ks++)
            af[ks] = *(const bf16x8*)&Wt[((size_t)l * FD + mo * 16 + lr) * FD + ks * 32 + lh * 8];
        float4 bs = *(const float4*)&bias[l * FD + mo * 16 + lh * 4];

        // prologue: gather chunk 0
        gather(0, agg[0]);
        __syncthreads();

        for (int c = 0; c < NN / CHK; c++) {
            int cur = c & 1;
            // ---- MFMA(c): m=out 128, n=dst 32, k=f 128 ----
            f32x4 cc = (f32x4){0.f, 0.f, 0.f, 0.f};
            {
                const unsigned short* ab = &agg[cur][(nd * 16 + lr) * PITCH + lh * 8];
                #pragma unroll
                for (int ks = 0; ks < 4; ks++) {
                    bf16x8 bfv = *(const bf16x8*)&ab[ks * 32];
                    cc = __builtin_amdgcn_mfma_f32_16x16x32_bf16(af[ks], bfv, cc, 0, 0, 0);
                }
            }
            // ---- epilogue: tanh((lin+b)*rdeg) -> cat (8B packed stores) ----
            {
                int dstl = c * CHK + nd * 16 + lr;
                float rd = __builtin_amdgcn_rcpf(degs[g0 + dstl]);
                float t0 = ftanh((cc[0] + bs.x) * rd);
                float t1 = ftanh((cc[1] + bs.y) * rd);
                float t2 = ftanh((cc[2] + bs.z) * rd);
                float t3 = ftanh((cc[3] + bs.w) * rd);
                uint2 pk;
                pk.x = (unsigned int)f2b(t0) | ((unsigned int)f2b(t1) << 16);
                pk.y = (unsigned int)f2b(t2) | ((unsigned int)f2b(t3) << 16);
                *(uint2*)&cat[(size_t)(g0 + dstl) * DD + l * FD + mo * 16 + lh * 4] = pk;
            }
            // ---- gather(c+1) into the other buffer ----
            if (c < NN / CHK - 1) gather(c + 1, agg[cur ^ 1]);
            __syncthreads();
        }

        // restage hW from this layer's output (L2-hot cat)
        if (l < NL - 1) {
            #pragma unroll
            for (int i = 0; i < 8; i++) {
                int u = tid + i * 1024;
                int row = u >> 4, cu = u & 15;
                uint4 v = *(const uint4*)&cat[(size_t)(g0 + row) * DD + l * FD + cu * 8];
                *(uint4*)&hW[row * PITCH + cu * 8] = v;
            }
            __syncthreads();
        }
    }
}

// ---------------- attention scores: bf16 MFMA GEMM + fused tanh/dot-v ----------------
// 1D grid 4096, XCD-swizzled so each XCD sweeps a contiguous m-range.
__global__ __launch_bounds__(256) void scores_k(
    const unsigned short* __restrict__ X,   // [TN][DD] bf16
    const unsigned short* __restrict__ Wt,  // [DD][DD] bf16, (n,k)
    const float* __restrict__ bv, const float* __restrict__ vv,
    float* __restrict__ sp)                 // [TN][8] partials
{
    __shared__ unsigned short sX[128][72];
    __shared__ unsigned short sW[128][72];
    int bid = blockIdx.x;
    int swz = (bid & 7) * 512 + (bid >> 3);   // 4096 blocks, 8 XCDs
    int bx = swz >> 2, by = swz & 3;
    int tid = threadIdx.x;
    int lane = tid & 63, wid = tid >> 6;
    int wm = wid >> 1, wn = wid & 1;
    int m0 = bx * 128;
    int n0 = by * 128;
    int lr = lane & 15, lh = lane >> 4;

    f32x4 acc[4][4];
    #pragma unroll
    for (int mi = 0; mi < 4; mi++)
        #pragma unroll
        for (int ni = 0; ni < 4; ni++)
            acc[mi][ni] = (f32x4){0.f, 0.f, 0.f, 0.f};

    for (int k0 = 0; k0 < DD; k0 += 64) {
        __syncthreads();
        #pragma unroll
        for (int i = 0; i < 4; i++) {
            int idx = tid + i * 256;
            int row = idx >> 3, ch = idx & 7;
            *(float4*)&sX[row][ch * 8] = *(const float4*)&X[(size_t)(m0 + row) * DD + k0 + ch * 8];
            *(float4*)&sW[row][ch * 8] = *(const float4*)&Wt[(size_t)(n0 + row) * DD + k0 + ch * 8];
        }
        __syncthreads();
        #pragma unroll
        for (int kk = 0; kk < 64; kk += 32) {
            bf16x8 af[4], bfr[4];
            #pragma unroll
            for (int mi = 0; mi < 4; mi++)
                af[mi] = *(const bf16x8*)&sX[wm * 64 + mi * 16 + lr][kk + lh * 8];
            #pragma unroll
            for (int ni = 0; ni < 4; ni++)
                bfr[ni] = *(const bf16x8*)&sW[wn * 64 + ni * 16 + lr][kk + lh * 8];
            #pragma unroll
            for (int mi = 0; mi < 4; mi++)
                #pragma unroll
                for (int ni = 0; ni < 4; ni++)
                    acc[mi][ni] = __builtin_amdgcn_mfma_f32_16x16x32_bf16(
                        af[mi], bfr[ni], acc[mi][ni], 0, 0, 0);
        }
    }

    float vcol[4], bcol[4];
    #pragma unroll
    for (int ni = 0; ni < 4; ni++) {
        int col = n0 + wn * 64 + ni * 16 + lr;
        vcol[ni] = vv[col];
        bcol[ni] = bv[col];
    }
    #pragma unroll
    for (int mi = 0; mi < 4; mi++) {
        #pragma unroll
        for (int r = 0; r < 4; r++) {
            float part = 0.f;
            #pragma unroll
            for (int ni = 0; ni < 4; ni++)
                part += ftanh(acc[mi][ni][r] + bcol[ni]) * vcol[ni];
            part += __shfl_xor(part, 1);
            part += __shfl_xor(part, 2);
            part += __shfl_xor(part, 4);
            part += __shfl_xor(part, 8);
            if (lr == 0) {
                int row = m0 + wm * 64 + mi * 16 + lh * 4 + r;
                sp[(size_t)row * 8 + by * 2 + wn] = part;
            }
        }
    }
}

// ---------------- softmax + pool v2: 512 threads, row-split accumulation ----------------
__global__ __launch_bounds__(512) void pool_k(
    const float* __restrict__ sp, const unsigned short* __restrict__ X,
    float* __restrict__ pooled)
{
    __shared__ float sattn[512];
    __shared__ float wmax[8];
    __shared__ float wsum[8];
    __shared__ float pred[512];
    int b = blockIdx.x, t = threadIdx.x;
    int lane = t & 63, wid = t >> 6;

    // score for node t (sum of 8 partials)
    float s;
    {
        const float4* p = (const float4*)&sp[((size_t)b * NN + t) * 8];
        float4 x = p[0], y = p[1];
        s = x.x + x.y + x.z + x.w + y.x + y.y + y.z + y.w;
    }
    float m = s;
    #pragma unroll
    for (int off = 1; off < 64; off <<= 1) m = fmaxf(m, __shfl_xor(m, off));
    if (lane == 0) wmax[wid] = m;
    __syncthreads();
    m = wmax[0];
    #pragma unroll
    for (int i = 1; i < 8; i++) m = fmaxf(m, wmax[i]);
    float e = expf(s - m);
    float ssum = e;
    #pragma unroll
    for (int off = 1; off < 64; off <<= 1) ssum += __shfl_xor(ssum, off);
    if (lane == 0) wsum[wid] = ssum;
    __syncthreads();
    float tot = wsum[0];
    #pragma unroll
    for (int i = 1; i < 8; i++) tot += wsum[i];
    sattn[t] = e * (1.0f / tot);
    __syncthreads();

    // pooling: rows split in two groups of 256; thread tc owns feat pair tc*2
    int rg = t >> 8, tc = t & 255;
    float2 acc = {0.f, 0.f};
    const unsigned short* Xb = X + (size_t)b * NN * DD;
    int n0 = rg * 256;
    #pragma unroll 4
    for (int n = n0; n < n0 + 256; n++) {
        float a = sattn[n];
        unsigned int px = *(const unsigned int*)&Xb[(size_t)n * DD + tc * 2];
        acc.x += a * b2f(px & 0xffff);
        acc.y += a * b2f(px >> 16);
    }
    if (rg == 1) { pred[tc * 2] = acc.x; pred[tc * 2 + 1] = acc.y; }
    __syncthreads();
    if (rg == 0) {
        pooled[b * DD + tc * 2 + 0] = acc.x + pred[tc * 2];
        pooled[b * DD + tc * 2 + 1] = acc.y + pred[tc * 2 + 1];
    }
}

// ---------------- output layer ----------------
__global__ void out_k(const float* __restrict__ pooled, const float* __restrict__ Wo,
                      const float* __restrict__ bo, float* __restrict__ out) {
    int b = blockIdx.x, c = threadIdx.x;  // 128 threads
    float acc = 0.f;
    const float* p = pooled + b * DD;
    for (int k = 0; k < DD; k++) acc += p[k] * Wo[k * 128 + c];
    out[b * 128 + c] = fmaxf(acc + bo[c], 0.f);
}

extern "C" void kernel_launch(void* const* d_in, const int* in_sizes, int n_in,
                              void* d_out, int out_size, void* d_ws, size_t ws_size,
                              hipStream_t stream)
{
    const float* node_feat = (const float*)d_in[0];
    const int*   edge_src  = (const int*)d_in[1];
    const int*   edge_dst  = (const int*)d_in[2];
    const float* conv_W    = (const float*)d_in[3];
    const float* conv_b    = (const float*)d_in[4];
    const float* att_W     = (const float*)d_in[5];
    const float* att_b     = (const float*)d_in[6];
    const float* att_v     = (const float*)d_in[7];
    const float* out_W     = (const float*)d_in[8];
    const float* out_b     = (const float*)d_in[9];
    float* out = (float*)d_out;
    (void)in_sizes; (void)n_in; (void)out_size;

    char* ws = (char*)d_ws;
    size_t off = 0;
    auto alloc = [&](size_t bytes) {
        void* p = ws + off;
        off += (bytes + 255) & ~(size_t)255;
        return p;
    };
    unsigned short* cat   = (unsigned short*)alloc((size_t)TN * DD * 2);  // bf16
    int*   counts  = (int*)alloc((size_t)TN * 4);
    int*   row_ptr = (int*)alloc((size_t)(TN + 1) * 4);
    int*   cursor  = (int*)alloc((size_t)TN * 4);
    int*   col_idx = (int*)alloc((size_t)NE * 4);
    float* degs    = (float*)alloc((size_t)TN * 4);
    float* sp      = (float*)alloc((size_t)TN * 8 * 4);
    unsigned short* attWt = (unsigned short*)alloc((size_t)DD * DD * 2);  // bf16
    unsigned short* convWt = (unsigned short*)alloc((size_t)NL * FD * FD * 2);
    float* pooled  = (float*)alloc((size_t)NB * DD * 4);
    if (off > ws_size) return;  // diagnostic guard

    hipMemsetAsync(counts, 0, (size_t)TN * 4, stream);
    count_k<<<NE / 256, 256, 0, stream>>>(edge_dst, counts);
    scan_b_k<<<NB, 512, 0, stream>>>(counts, row_ptr, cursor, degs);
    fill_k<<<NE / 256, 256, 0, stream>>>(edge_src, edge_dst, cursor, col_idx);
    transpose_cast_k<<<dim3(DD / 32, DD / 32), 256, 0, stream>>>(att_W, attWt);
    transp_convW_k<<<dim3(FD / 32, FD / 32, NL), 256, 0, stream>>>(conv_W, convWt);

    conv_all_k<<<NB, 1024, 0, stream>>>(node_feat, convWt, conv_b,
                                        row_ptr, col_idx, degs, cat);

    scores_k<<<4096, 256, 0, stream>>>(cat, attWt, att_b, att_v, sp);
    pool_k<<<NB, 512, 0, stream>>>(sp, cat, pooled);
    out_k<<<NB, 128, 0, stream>>>(pooled, out_W, out_b, out);
}

// Round 11
// 479.901 us; speedup vs baseline: 1.4771x; 1.0049x over previous
//
#include <hip/hip_runtime.h>
#include <hip/hip_bf16.h>

#define TN 131072      // total nodes (B*N)
#define NB 256         // batches
#define NN 512         // nodes per batch
#define FD 128         // per-layer feature dim
#define DD 512         // concat dim
#define NE 2097152     // edges
#define NL 4           // layers
#define PITCH 136      // LDS row pitch in bf16 units (272 B)
#define CHK 32         // dst nodes per chunk (double-buffered agg)
#define NCH 16         // chunks per batch
#define CICAP 832      // staged edge-offsets per chunk (exp 544, +12 sigma)

typedef __attribute__((ext_vector_type(8))) short bf16x8;
typedef __attribute__((ext_vector_type(4))) float f32x4;

__device__ __forceinline__ float b2f(unsigned int u) {
    union { unsigned int i; float f; } c; c.i = u << 16; return c.f;
}
__device__ __forceinline__ unsigned short f2b(float f) {
    union { float f; unsigned int i; } c; c.f = f;
    unsigned int x = c.i;
    return (unsigned short)((x + 0x7fffu + ((x >> 16) & 1u)) >> 16);  // RNE
}
__device__ __forceinline__ void add2(float& a0, float& a1, unsigned int v) {
    union { unsigned int u; float f; } lo, hi;
    lo.u = v << 16; hi.u = v & 0xffff0000u;
    a0 += lo.f; a1 += hi.f;
}
__device__ __forceinline__ void set2(float& a0, float& a1, unsigned int v) {
    union { unsigned int u; float f; } lo, hi;
    lo.u = v << 16; hi.u = v & 0xffff0000u;
    a0 = lo.f; a1 = hi.f;
}
__device__ __forceinline__ uint4 packv8(const float* a) {
    uint4 p;
    p.x = (unsigned int)f2b(a[0]) | ((unsigned int)f2b(a[1]) << 16);
    p.y = (unsigned int)f2b(a[2]) | ((unsigned int)f2b(a[3]) << 16);
    p.z = (unsigned int)f2b(a[4]) | ((unsigned int)f2b(a[5]) << 16);
    p.w = (unsigned int)f2b(a[6]) | ((unsigned int)f2b(a[7]) << 16);
    return p;
}
// fast tanh: (e^{2x}-1)/(e^{2x}+1), clamped (bf16-exact saturation)
__device__ __forceinline__ float ftanh(float x) {
    float xc = fminf(fmaxf(x, -9.0f), 9.0f);
    float e = __expf(2.0f * xc);
    return (e - 1.0f) * __builtin_amdgcn_rcpf(e + 1.0f);
}
// async global->LDS, 16B per lane
__device__ __forceinline__ void gl_lds16(const unsigned short* g, unsigned short* l) {
    __builtin_amdgcn_global_load_lds(
        (const __attribute__((address_space(1))) unsigned int*)g,
        (__attribute__((address_space(3))) unsigned int*)l,
        16, 0, 0);
}

// ---------------- CSR build ----------------
__global__ void count_k(const int* __restrict__ dst, int* __restrict__ counts) {
    int e = blockIdx.x * blockDim.x + threadIdx.x;
    if (e < NE) atomicAdd(&counts[dst[e]], 1);
}

__global__ __launch_bounds__(512) void scan_b_k(const int* __restrict__ counts,
                                                int* __restrict__ row_ptr,
                                                int* __restrict__ cursor,
                                                float* __restrict__ degs) {
    __shared__ int ss[512];
    int b = blockIdx.x, t = threadIdx.x;
    int gid = b * NN + t;
    int c = counts[gid];
    ss[t] = c;
    __syncthreads();
    for (int off = 1; off < 512; off <<= 1) {
        int v = (t >= off) ? ss[t - off] : 0;
        __syncthreads();
        ss[t] += v;
        __syncthreads();
    }
    int excl = ss[t] - c;
    int base = b * (NN * 16) + excl;   // DEG=16
    row_ptr[gid] = base;
    cursor[gid]  = base;
    degs[gid]    = (float)(c + 1);
    if (b == NB - 1 && t == NN - 1) row_ptr[TN] = NE;
}

// writes precomputed LDS byte offsets: (src - batch_base) * PITCH * 2
__global__ void fill_k(const int* __restrict__ src, const int* __restrict__ dst,
                       int* __restrict__ cursor, int* __restrict__ col_off) {
    int e = blockIdx.x * blockDim.x + threadIdx.x;
    if (e < NE) {
        int d = dst[e];
        int p = atomicAdd(&cursor[d], 1);
        col_off[p] = (src[e] - (d & ~(NN - 1))) * (PITCH * 2);
    }
}

// ---------------- att_W transpose + bf16 cast:  Wt[n][k] = bf16(W[k][n]) ----------------
__global__ __launch_bounds__(256) void transpose_cast_k(const float* __restrict__ W,
                                                        unsigned short* __restrict__ Wt) {
    __shared__ float tile[32][33];
    int k0 = blockIdx.x * 32, n0 = blockIdx.y * 32;
    int tx = threadIdx.x & 31, ty = threadIdx.x >> 5;  // 32 x 8
    #pragma unroll
    for (int i = 0; i < 32; i += 8)
        tile[ty + i][tx] = W[(size_t)(k0 + ty + i) * DD + n0 + tx];
    __syncthreads();
    #pragma unroll
    for (int i = 0; i < 32; i += 8)
        Wt[(size_t)(n0 + ty + i) * DD + k0 + tx] = f2b(tile[tx][ty + i]);
}

// ---------------- conv_W transpose + bf16 cast per layer: Wt_l[o][f] = bf16(W_l[f][o]) ----
__global__ __launch_bounds__(256) void transp_convW_k(const float* __restrict__ W,
                                                      unsigned short* __restrict__ Wt) {
    __shared__ float tile[32][33];
    const float* Wl = W + (size_t)blockIdx.z * FD * FD;
    unsigned short* Wtl = Wt + (size_t)blockIdx.z * FD * FD;
    int f0 = blockIdx.x * 32, o0 = blockIdx.y * 32;
    int tx = threadIdx.x & 31, ty = threadIdx.x >> 5;
    #pragma unroll
    for (int i = 0; i < 32; i += 8)
        tile[ty + i][tx] = Wl[(size_t)(f0 + ty + i) * FD + o0 + tx];
    __syncthreads();
    #pragma unroll
    for (int i = 0; i < 32; i += 8)
        Wtl[(size_t)(o0 + ty + i) * FD + f0 + tx] = f2b(tile[tx][ty + i]);
}

// ---------------- fused all-layer conv v7: LDS-staged edge offsets, dbuf agg ----------------
// One block per batch, 1024 threads (16 waves). hW window in LDS (pitch-136).
// Chunk = 32 dst, agg double-buffered. Edge byte-offsets staged 2 chunks ahead
// into rolling ciL[2] (VMEM latency hides under MFMA+epilogue+gather).
__global__ __launch_bounds__(1024) void conv_all_k(
    const float* __restrict__ node_feat,      // [TN][FD] fp32
    const unsigned short* __restrict__ Wt,    // [NL*FD][FD] bf16 (out,f)
    const float* __restrict__ bias,           // [NL*FD]
    const int* __restrict__ rp, const int* __restrict__ coff,
    const float* __restrict__ degs,
    unsigned short* __restrict__ cat)         // [TN][DD] bf16
{
    __shared__ unsigned short hW[NN * PITCH];        // 139,264 B
    __shared__ unsigned short agg[2][CHK * PITCH];   // 17,408 B
    __shared__ int ciL[2][CICAP];                    // 6,656 B
    const int tid = threadIdx.x;
    const int g0 = blockIdx.x * NN;
    const int lane = tid & 63, w = tid >> 6;
    const int lr = lane & 15, lh = lane >> 4;
    const int mo = w >> 1, nd = w & 1;     // mfma: 8(out-tiles) x 2(dst-tiles)
    const int gn = tid >> 5;               // gather: node in chunk (0..31)
    const int gs = tid & 31;               // gather: 8B unit (4 feats) in row
    const char* hWb = (const char*)hW;

    // initial stage: node_feat fp32 -> hW bf16
    #pragma unroll
    for (int i = 0; i < 8; i++) {
        int u = tid + i * 1024;
        int row = u >> 4, cu = u & 15;
        const float4* s4 = (const float4*)(node_feat + (size_t)(g0 + row) * FD + cu * 8);
        float4 x = s4[0], y = s4[1];
        float tmp[8] = {x.x, x.y, x.z, x.w, y.x, y.y, y.z, y.w};
        *(uint4*)&hW[row * PITCH + cu * 8] = packv8(tmp);
    }
    __syncthreads();

    // gather one node's aggregation (32 lanes/node, offsets from LDS)
    auto do_gather = [&](int nl, int rs, int re, int eb, const int* cib,
                         unsigned short* buf) {
        const char* rowb = hWb + nl * (PITCH * 2);
        uint2 v = *(const uint2*)(rowb + gs * 8);
        float a0, a1, a2, a3;
        set2(a0, a1, v.x); set2(a2, a3, v.y);
        int r1 = re;
        int rlim = eb + CICAP; if (r1 > rlim) r1 = rlim;
        int j = rs;
        for (; j + 8 <= r1; j += 8) {
            int off[8];
            #pragma unroll
            for (int i = 0; i < 8; i++) off[i] = cib[j - eb + i];
            uint2 u[8];
            #pragma unroll
            for (int i = 0; i < 8; i++) u[i] = *(const uint2*)(hWb + off[i] + gs * 8);
            #pragma unroll
            for (int i = 0; i < 8; i++) { add2(a0, a1, u[i].x); add2(a2, a3, u[i].y); }
        }
        for (; j < r1; j++) {
            int off = cib[j - eb];
            uint2 u = *(const uint2*)(hWb + off + gs * 8);
            add2(a0, a1, u.x); add2(a2, a3, u.y);
        }
        for (; j < re; j++) {      // rare overflow tail: offsets from global
            int off = coff[j];
            uint2 u = *(const uint2*)(hWb + off + gs * 8);
            add2(a0, a1, u.x); add2(a2, a3, u.y);
        }
        uint2 pk;
        pk.x = (unsigned int)f2b(a0) | ((unsigned int)f2b(a1) << 16);
        pk.y = (unsigned int)f2b(a2) | ((unsigned int)f2b(a3) << 16);
        *(uint2*)&buf[gn * PITCH + gs * 4] = pk;
    };

    for (int l = 0; l < NL; l++) {
        // Wt fragments (A operand, m=out) + bias in regs for the whole layer
        bf16x8 af[4];
        #pragma unroll
        for (int ks = 0; ks < 4; ks++)
            af[ks] = *(const bf16x8*)&Wt[((size_t)l * FD + mo * 16 + lr) * FD + ks * 32 + lh * 8];
        float4 bs = *(const float4*)&bias[l * FD + mo * 16 + lh * 4];

        // prologue: stage ciL[0], ciL[1]; gather chunk 0
        {
            int eb0 = rp[g0];
            int cnt0 = rp[g0 + CHK] - eb0;      if (cnt0 > CICAP) cnt0 = CICAP;
            int eb1 = rp[g0 + CHK];
            int cnt1 = rp[g0 + 2 * CHK] - eb1;  if (cnt1 > CICAP) cnt1 = CICAP;
            int rs0 = rp[g0 + gn], re0 = rp[g0 + gn + 1];
            if (tid < cnt0) ciL[0][tid] = coff[eb0 + tid];
            if (tid < cnt1) ciL[1][tid] = coff[eb1 + tid];
            __syncthreads();
            do_gather(gn, rs0, re0, eb0, ciL[0], agg[0]);
        }
        __syncthreads();

        for (int c = 0; c < NCH; c++) {
            int cur = c & 1;
            // prefetch next-gather bounds (issued early, consumed after MFMA)
            int rs_n = 0, re_n = 0, eb_n = 0;
            if (c < NCH - 1) {
                eb_n = rp[g0 + (c + 1) * CHK];
                rs_n = rp[g0 + (c + 1) * CHK + gn];
                re_n = rp[g0 + (c + 1) * CHK + gn + 1];
            }
            // stage-load offsets for chunk c+2 (committed to LDS after epilogue)
            int scnt = 0, sval = 0;
            if (c <= NCH - 3) {
                int eb2 = rp[g0 + (c + 2) * CHK];
                scnt = rp[g0 + (c + 3) * CHK] - eb2; if (scnt > CICAP) scnt = CICAP;
                if (tid < scnt) sval = coff[eb2 + tid];
            }
            // ---- MFMA(c): m=out 128, n=dst 32, k=f 128 ----
            f32x4 cc = (f32x4){0.f, 0.f, 0.f, 0.f};
            {
                const unsigned short* ab = &agg[cur][(nd * 16 + lr) * PITCH + lh * 8];
                #pragma unroll
                for (int ks = 0; ks < 4; ks++) {
                    bf16x8 bfv = *(const bf16x8*)&ab[ks * 32];
                    cc = __builtin_amdgcn_mfma_f32_16x16x32_bf16(af[ks], bfv, cc, 0, 0, 0);
                }
            }
            // ---- epilogue: tanh((lin+b)*rdeg) -> cat (8B packed stores) ----
            {
                int dstl = c * CHK + nd * 16 + lr;
                float rd = __builtin_amdgcn_rcpf(degs[g0 + dstl]);
                float t0 = ftanh((cc[0] + bs.x) * rd);
                float t1 = ftanh((cc[1] + bs.y) * rd);
                float t2 = ftanh((cc[2] + bs.z) * rd);
                float t3 = ftanh((cc[3] + bs.w) * rd);
                uint2 pk;
                pk.x = (unsigned int)f2b(t0) | ((unsigned int)f2b(t1) << 16);
                pk.y = (unsigned int)f2b(t2) | ((unsigned int)f2b(t3) << 16);
                *(uint2*)&cat[(size_t)(g0 + dstl) * DD + l * FD + mo * 16 + lh * 4] = pk;
            }
            // commit staged offsets for c+2 into ciL[(c+2)&1] == ciL[cur]
            if (tid < scnt) ciL[cur][tid] = sval;
            // ---- gather(c+1) into the other agg buffer ----
            if (c < NCH - 1)
                do_gather((c + 1) * CHK + gn, rs_n, re_n, eb_n, ciL[(c + 1) & 1], agg[cur ^ 1]);
            __syncthreads();
        }

        // restage hW from this layer's output (L2-hot cat)
        if (l < NL - 1) {
            #pragma unroll
            for (int i = 0; i < 8; i++) {
                int u = tid + i * 1024;
                int row = u >> 4, cu = u & 15;
                uint4 v = *(const uint4*)&cat[(size_t)(g0 + row) * DD + l * FD + cu * 8];
                *(uint4*)&hW[row * PITCH + cu * 8] = v;
            }
            __syncthreads();
        }
    }
}

// ---------------- attention scores v2: global_load_lds staging (m97 structure) ----------------
// 1D grid 4096, XCD-swizzled. Linear LDS tiles [128][64] bf16, width-16 async stage.
__global__ __launch_bounds__(256) void scores_k(
    const unsigned short* __restrict__ X,   // [TN][DD] bf16
    const unsigned short* __restrict__ Wt,  // [DD][DD] bf16, (n,k)
    const float* __restrict__ bv, const float* __restrict__ vv,
    float* __restrict__ sp)                 // [TN][8] partials
{
    __shared__ unsigned short sXl[128 * 64];   // 16 KB
    __shared__ unsigned short sWl[128 * 64];   // 16 KB
    int bid = blockIdx.x;
    int swz = (bid & 7) * 512 + (bid >> 3);   // 4096 blocks, 8 XCDs
    int bx = swz >> 2, by = swz & 3;
    int tid = threadIdx.x;
    int lane = tid & 63, wid = tid >> 6;
    int wm = wid >> 1, wn = wid & 1;
    int m0 = bx * 128;
    int n0 = by * 128;
    int lr = lane & 15, lh = lane >> 4;

    f32x4 acc[4][4];
    #pragma unroll
    for (int mi = 0; mi < 4; mi++)
        #pragma unroll
        for (int ni = 0; ni < 4; ni++)
            acc[mi][ni] = (f32x4){0.f, 0.f, 0.f, 0.f};

    for (int k0 = 0; k0 < DD; k0 += 64) {
        __syncthreads();
        #pragma unroll
        for (int i = 0; i < 4; i++) {
            int u = (i << 8) + tid;
            int row = u >> 3, cu = u & 7;
            gl_lds16(&X[(size_t)(m0 + row) * DD + k0 + cu * 8], &sXl[u * 8]);
            gl_lds16(&Wt[(size_t)(n0 + row) * DD + k0 + cu * 8], &sWl[u * 8]);
        }
        __syncthreads();
        #pragma unroll
        for (int kk = 0; kk < 64; kk += 32) {
            bf16x8 afv[4], bfv[4];
            #pragma unroll
            for (int mi = 0; mi < 4; mi++)
                afv[mi] = *(const bf16x8*)&sXl[(wm * 64 + mi * 16 + lr) * 64 + kk + lh * 8];
            #pragma unroll
            for (int ni = 0; ni < 4; ni++)
                bfv[ni] = *(const bf16x8*)&sWl[(wn * 64 + ni * 16 + lr) * 64 + kk + lh * 8];
            #pragma unroll
            for (int mi = 0; mi < 4; mi++)
                #pragma unroll
                for (int ni = 0; ni < 4; ni++)
                    acc[mi][ni] = __builtin_amdgcn_mfma_f32_16x16x32_bf16(
                        afv[mi], bfv[ni], acc[mi][ni], 0, 0, 0);
        }
    }

    float vcol[4], bcol[4];
    #pragma unroll
    for (int ni = 0; ni < 4; ni++) {
        int col = n0 + wn * 64 + ni * 16 + lr;
        vcol[ni] = vv[col];
        bcol[ni] = bv[col];
    }
    #pragma unroll
    for (int mi = 0; mi < 4; mi++) {
        #pragma unroll
        for (int r = 0; r < 4; r++) {
            float part = 0.f;
            #pragma unroll
            for (int ni = 0; ni < 4; ni++)
                part += ftanh(acc[mi][ni][r] + bcol[ni]) * vcol[ni];
            part += __shfl_xor(part, 1);
            part += __shfl_xor(part, 2);
            part += __shfl_xor(part, 4);
            part += __shfl_xor(part, 8);
            if (lr == 0) {
                int row = m0 + wm * 64 + mi * 16 + lh * 4 + r;
                sp[(size_t)row * 8 + by * 2 + wn] = part;
            }
        }
    }
}

// ---------------- softmax + pool v2: 512 threads, row-split accumulation ----------------
__global__ __launch_bounds__(512) void pool_k(
    const float* __restrict__ sp, const unsigned short* __restrict__ X,
    float* __restrict__ pooled)
{
    __shared__ float sattn[512];
    __shared__ float wmax[8];
    __shared__ float wsum[8];
    __shared__ float pred[512];
    int b = blockIdx.x, t = threadIdx.x;
    int lane = t & 63, wid = t >> 6;

    float s;
    {
        const float4* p = (const float4*)&sp[((size_t)b * NN + t) * 8];
        float4 x = p[0], y = p[1];
        s = x.x + x.y + x.z + x.w + y.x + y.y + y.z + y.w;
    }
    float m = s;
    #pragma unroll
    for (int off = 1; off < 64; off <<= 1) m = fmaxf(m, __shfl_xor(m, off));
    if (lane == 0) wmax[wid] = m;
    __syncthreads();
    m = wmax[0];
    #pragma unroll
    for (int i = 1; i < 8; i++) m = fmaxf(m, wmax[i]);
    float e = expf(s - m);
    float ssum = e;
    #pragma unroll
    for (int off = 1; off < 64; off <<= 1) ssum += __shfl_xor(ssum, off);
    if (lane == 0) wsum[wid] = ssum;
    __syncthreads();
    float tot = wsum[0];
    #pragma unroll
    for (int i = 1; i < 8; i++) tot += wsum[i];
    sattn[t] = e * (1.0f / tot);
    __syncthreads();

    int rg = t >> 8, tc = t & 255;
    float2 acc = {0.f, 0.f};
    const unsigned short* Xb = X + (size_t)b * NN * DD;
    int n0 = rg * 256;
    #pragma unroll 4
    for (int n = n0; n < n0 + 256; n++) {
        float a = sattn[n];
        unsigned int px = *(const unsigned int*)&Xb[(size_t)n * DD + tc * 2];
        acc.x += a * b2f(px & 0xffff);
        acc.y += a * b2f(px >> 16);
    }
    if (rg == 1) { pred[tc * 2] = acc.x; pred[tc * 2 + 1] = acc.y; }
    __syncthreads();
    if (rg == 0) {
        pooled[b * DD + tc * 2 + 0] = acc.x + pred[tc * 2];
        pooled[b * DD + tc * 2 + 1] = acc.y + pred[tc * 2 + 1];
    }
}

// ---------------- output layer ----------------
__global__ void out_k(const float* __restrict__ pooled, const float* __restrict__ Wo,
                      const float* __restrict__ bo, float* __restrict__ out) {
    int b = blockIdx.x, c = threadIdx.x;  // 128 threads
    float acc = 0.f;
    const float* p = pooled + b * DD;
    for (int k = 0; k < DD; k++) acc += p[k] * Wo[k * 128 + c];
    out[b * 128 + c] = fmaxf(acc + bo[c], 0.f);
}

extern "C" void kernel_launch(void* const* d_in, const int* in_sizes, int n_in,
                              void* d_out, int out_size, void* d_ws, size_t ws_size,
                              hipStream_t stream)
{
    const float* node_feat = (const float*)d_in[0];
    const int*   edge_src  = (const int*)d_in[1];
    const int*   edge_dst  = (const int*)d_in[2];
    const float* conv_W    = (const float*)d_in[3];
    const float* conv_b    = (const float*)d_in[4];
    const float* att_W     = (const float*)d_in[5];
    const float* att_b     = (const float*)d_in[6];
    const float* att_v     = (const float*)d_in[7];
    const float* out_W     = (const float*)d_in[8];
    const float* out_b     = (const float*)d_in[9];
    float* out = (float*)d_out;
    (void)in_sizes; (void)n_in; (void)out_size;

    char* ws = (char*)d_ws;
    size_t off = 0;
    auto alloc = [&](size_t bytes) {
        void* p = ws + off;
        off += (bytes + 255) & ~(size_t)255;
        return p;
    };
    unsigned short* cat   = (unsigned short*)alloc((size_t)TN * DD * 2);  // bf16
    int*   counts  = (int*)alloc((size_t)TN * 4);
    int*   row_ptr = (int*)alloc((size_t)(TN + 1) * 4);
    int*   cursor  = (int*)alloc((size_t)TN * 4);
    int*   col_off = (int*)alloc((size_t)NE * 4);
    float* degs    = (float*)alloc((size_t)TN * 4);
    float* sp      = (float*)alloc((size_t)TN * 8 * 4);
    unsigned short* attWt = (unsigned short*)alloc((size_t)DD * DD * 2);  // bf16
    unsigned short* convWt = (unsigned short*)alloc((size_t)NL * FD * FD * 2);
    float* pooled  = (float*)alloc((size_t)NB * DD * 4);
    if (off > ws_size) return;  // diagnostic guard

    hipMemsetAsync(counts, 0, (size_t)TN * 4, stream);
    count_k<<<NE / 256, 256, 0, stream>>>(edge_dst, counts);
    scan_b_k<<<NB, 512, 0, stream>>>(counts, row_ptr, cursor, degs);
    fill_k<<<NE / 256, 256, 0, stream>>>(edge_src, edge_dst, cursor, col_off);
    transpose_cast_k<<<dim3(DD / 32, DD / 32), 256, 0, stream>>>(att_W, attWt);
    transp_convW_k<<<dim3(FD / 32, FD / 32, NL), 256, 0, stream>>>(conv_W, convWt);

    conv_all_k<<<NB, 1024, 0, stream>>>(node_feat, convWt, conv_b,
                                        row_ptr, col_off, degs, cat);

    scores_k<<<4096, 256, 0, stream>>>(cat, attWt, att_b, att_v, sp);
    pool_k<<<NB, 512, 0, stream>>>(sp, cat, pooled);
    out_k<<<NB, 128, 0, stream>>>(pooled, out_W, out_b, out);
}